// Round 2
// baseline (471.258 us; speedup 1.0000x reference)
//
#include <hip/hip_runtime.h>
#include <hip/hip_bf16.h>

#define NN 3072
#define DM 256
#define NH 8
#define HDIM 32
#define NE 98304
#define DFF 1024
#define MAXDEG 512

typedef short bf16x8 __attribute__((ext_vector_type(8)));
typedef float f32x4 __attribute__((ext_vector_type(4)));
typedef unsigned short u16;
typedef unsigned int u32;

#define MFMA16 __builtin_amdgcn_mfma_f32_16x16x32_bf16

__device__ __forceinline__ u16 f2bf(float f){
  u32 u = __builtin_bit_cast(u32, f);
  u32 r = (u + 0x7FFFu + ((u >> 16) & 1u)) >> 16;
  return (u16)r;
}

// ---------------- degree count ----------------
__global__ void k_deg(const int* __restrict__ src, const int* __restrict__ dst,
                      int* __restrict__ deg_out, int* __restrict__ deg_in){
  int e = blockIdx.x * 256 + threadIdx.x;
  if (e < NE){
    atomicAdd(&deg_out[src[e]], 1);
    atomicAdd(&deg_in[dst[e]], 1);
  }
}

// ---------------- exclusive scan of deg_out -> row_ptr (3073) ----------------
__global__ __launch_bounds__(1024)
void k_scan(const int* __restrict__ deg, int* __restrict__ row_ptr){
  __shared__ int sc[1024];
  int t = threadIdx.x;
  int a = deg[t*3], b = deg[t*3+1], c = deg[t*3+2];
  int s = a + b + c;
  sc[t] = s;
  __syncthreads();
  for (int off = 1; off < 1024; off <<= 1){
    int v = (t >= off) ? sc[t-off] : 0;
    __syncthreads();
    sc[t] += v;
    __syncthreads();
  }
  int incl = sc[t];
  int excl = incl - s;
  row_ptr[t*3]   = excl;
  row_ptr[t*3+1] = excl + a;
  row_ptr[t*3+2] = excl + a + b;
  if (t == 1023) row_ptr[NN] = incl;
}

// ---------------- scatter edges into CSR ----------------
__global__ void k_scatter(const int* __restrict__ src, const int* __restrict__ dst,
                          const int* __restrict__ types, const float* __restrict__ w,
                          const int* __restrict__ row_ptr, int* __restrict__ fill,
                          u32* __restrict__ emeta, float* __restrict__ ew){
  int e = blockIdx.x * 256 + threadIdx.x;
  if (e < NE){
    int s = src[e];
    int slot = row_ptr[s] + atomicAdd(&fill[s], 1);
    emeta[slot] = ((u32)types[e] << 24) | ((u32)dst[e] << 12) | (u32)s;
    ew[slot] = w[e];
  }
}

// ---------------- weight transpose+convert to bf16 ----------------
__global__ void k_conv(const float* __restrict__ Wq, const float* __restrict__ Wk,
                       const float* __restrict__ Wv, const float* __restrict__ Wo,
                       const float* __restrict__ W1, const float* __restrict__ W2,
                       u16* __restrict__ Wqt, u16* __restrict__ Wkt, u16* __restrict__ Wvt,
                       u16* __restrict__ Wot, u16* __restrict__ W1t, u16* __restrict__ W2t){
  int idx = blockIdx.x * 256 + threadIdx.x;   // 0 .. 786431
  if (idx < 262144){
    int m = idx >> 16, off = idx & 65535;
    int k = off >> 8, n = off & 255;
    const float* W = (m==0) ? Wq : (m==1) ? Wk : (m==2) ? Wv : Wo;
    u16* Wt = (m==0) ? Wqt : (m==1) ? Wkt : (m==2) ? Wvt : Wot;
    Wt[n*256 + k] = f2bf(W[off]);
  } else if (idx < 524288){
    int off = idx - 262144;            // W1: [256][1024]
    int k = off >> 10, n = off & 1023;
    W1t[n*256 + k] = f2bf(W1[off]);
  } else {
    int off = idx - 524288;            // W2: [1024][256]
    int k = off >> 8, n = off & 255;
    W2t[n*1024 + k] = f2bf(W2[off]);
  }
}

// ---------------- LayerNorm (optionally fused degree-embedding add) ----------------
__global__ __launch_bounds__(256)
void k_ln(const float* __restrict__ in, const int* __restrict__ deg_in,
          const int* __restrict__ deg_out, const float* __restrict__ in_emb,
          const float* __restrict__ out_emb, const float* __restrict__ dscale,
          const float* __restrict__ g, const float* __restrict__ b,
          float* __restrict__ save_f32, u16* __restrict__ out_bf){
  int i = blockIdx.x, c = threadIdx.x;
  size_t idx = (size_t)i*DM + c;
  float val = in[idx];
  if (deg_in){
    int di = min(deg_in[i], MAXDEG), dg = min(deg_out[i], MAXDEG);
    val += (in_emb[(size_t)di*DM + c] + out_emb[(size_t)dg*DM + c]) * dscale[0];
    save_f32[idx] = val;
  }
  float s = val, s2 = val*val;
  #pragma unroll
  for (int off = 32; off; off >>= 1){
    s  += __shfl_xor(s, off);
    s2 += __shfl_xor(s2, off);
  }
  __shared__ float red[8];
  int lane = c & 63, w = c >> 6;
  if (lane == 0){ red[w] = s; red[4+w] = s2; }
  __syncthreads();
  s  = red[0] + red[1] + red[2] + red[3];
  s2 = red[4] + red[5] + red[6] + red[7];
  float mean = s * (1.f/256.f);
  float var = s2 * (1.f/256.f) - mean*mean;
  float xn = (val - mean) * rsqrtf(var + 1e-5f) * g[c] + b[c];
  out_bf[idx] = f2bf(xn);
}

// ---------------- generic MFMA GEMM: C = A[M][K] * Bt[N][K]^T, fused epilogues ----------------
// mode 0: u16 out = bf16(val)                 (Q, K)
// mode 1: u16 out[col*NN + row] = bf16(val)   (V -> vT)
// mode 2: f32 out = res + val                 (Wo -> x2)
// mode 3: u16 out = bf16(gelu(val))           (FFN1)
// mode 4: f32 out = res + val                 (FFN2 -> final, f32 output)
__global__ __launch_bounds__(256)
void k_gemm(const u16* __restrict__ A, const u16* __restrict__ Bt,
            const float* __restrict__ bias, const float* __restrict__ res,
            void* __restrict__ out, int K, int Ncols, int mode){
  __shared__ u16 sA[64][40];
  __shared__ u16 sB[64][40];
  const int tid = threadIdx.x, lane = tid & 63, wid = tid >> 6;
  const int m0 = blockIdx.y * 64, n0 = blockIdx.x * 64;
  const int wr = (wid >> 1) * 32, wc = (wid & 1) * 32;
  const int srow = tid >> 2, scol = (tid & 3) * 8;
  const int fr = lane & 15, fg = lane >> 4;
  f32x4 acc00 = {0,0,0,0}, acc01 = {0,0,0,0}, acc10 = {0,0,0,0}, acc11 = {0,0,0,0};
  for (int k0 = 0; k0 < K; k0 += 32){
    __syncthreads();
    *(bf16x8*)&sA[srow][scol] = *(const bf16x8*)&A[(size_t)(m0+srow)*K + k0 + scol];
    *(bf16x8*)&sB[srow][scol] = *(const bf16x8*)&Bt[(size_t)(n0+srow)*K + k0 + scol];
    __syncthreads();
    bf16x8 a0 = *(const bf16x8*)&sA[wr + fr][fg*8];
    bf16x8 a1 = *(const bf16x8*)&sA[wr + 16 + fr][fg*8];
    bf16x8 b0 = *(const bf16x8*)&sB[wc + fr][fg*8];
    bf16x8 b1 = *(const bf16x8*)&sB[wc + 16 + fr][fg*8];
    acc00 = MFMA16(a0, b0, acc00, 0, 0, 0);
    acc01 = MFMA16(a0, b1, acc01, 0, 0, 0);
    acc10 = MFMA16(a1, b0, acc10, 0, 0, 0);
    acc11 = MFMA16(a1, b1, acc11, 0, 0, 0);
  }
  #pragma unroll
  for (int fm = 0; fm < 2; fm++)
  #pragma unroll
  for (int fn = 0; fn < 2; fn++){
    f32x4 c = (fm==0) ? ((fn==0) ? acc00 : acc01) : ((fn==0) ? acc10 : acc11);
    #pragma unroll
    for (int r = 0; r < 4; r++){
      int row = m0 + wr + fm*16 + fg*4 + r;
      int col = n0 + wc + fn*16 + fr;
      float val = c[r] + bias[col];
      size_t idx = (size_t)row*Ncols + col;
      if (mode == 0)      ((u16*)out)[idx] = f2bf(val);
      else if (mode == 1) ((u16*)out)[(size_t)col*NN + row] = f2bf(val);
      else if (mode == 2) ((float*)out)[idx] = res[idx] + val;
      else if (mode == 3) ((u16*)out)[idx] = f2bf(0.5f*val*(1.f + erff(val*0.70710678f)));
      else                ((float*)out)[idx] = res[idx] + val;
    }
  }
}

// ---------------- fused bias + flash attention ----------------
// WG = 512 threads = 8 waves; wave h handles head h for 16 query rows.
__global__ __launch_bounds__(512)
void k_attn(const u16* __restrict__ qb, const u16* __restrict__ kb, const u16* __restrict__ vT,
            const float* __restrict__ pos, const float* __restrict__ spd_table,
            const float* __restrict__ ett, const float* __restrict__ slb,
            const u32* __restrict__ emeta, const float* __restrict__ ew,
            const int* __restrict__ row_ptr, u16* __restrict__ aob){
  __shared__ float s_sc[NH][16][36];
  __shared__ u16   s_p[NH][16][40];
  __shared__ float s_fac[NH][16];
  __shared__ float s_spd[96];
  __shared__ float s_ett[128];
  __shared__ float s_slb[8];
  __shared__ u32   s_em[1024];
  __shared__ float s_ew[1024];

  const int tid = threadIdx.x, lane = tid & 63, h = tid >> 6;
  const int i0 = blockIdx.x * 16;
  const float SCORE_SCALE = 0.70710678f;   // 1/(0.25*sqrt(32))

  if (tid < 96) s_spd[tid] = spd_table[tid] * 10.f;           // pre-scaled by BIAS_SCALE
  else if (tid >= 128 && tid < 256) s_ett[tid-128] = ett[tid-128] * 10.f;
  else if (tid >= 256 && tid < 264) s_slb[tid-256] = slb[tid-256];

  const int e0 = row_ptr[i0], e1 = row_ptr[i0+16];
  const int ne = min(e1 - e0, 1024);
  for (int ix = tid; ix < ne; ix += 512){ s_em[ix] = emeta[e0+ix]; s_ew[ix] = ew[e0+ix]; }

  const int fr = lane & 15, fg = lane >> 4;   // fragment row / k-group
  const int sr = lane >> 2, sg = lane & 3;    // softmax row / col-group
  bf16x8 qv = *(const bf16x8*)&qb[(size_t)(i0 + fr)*DM + h*HDIM + fg*8];
  f32x4 o0 = {0,0,0,0}, o1 = {0,0,0,0};
  float m_run = -INFINITY, l_run = 0.f;
  __syncthreads();

  for (int j0 = 0; j0 < NN; j0 += 32){
    // ---- QK^T for this head (two 16-col fragments) ----
    bf16x8 kf0 = *(const bf16x8*)&kb[(size_t)(j0 + fr)*DM + h*HDIM + fg*8];
    bf16x8 kf1 = *(const bf16x8*)&kb[(size_t)(j0 + 16 + fr)*DM + h*HDIM + fg*8];
    f32x4 z = {0,0,0,0};
    f32x4 s0 = MFMA16(qv, kf0, z, 0, 0, 0);
    f32x4 s1 = MFMA16(qv, kf1, z, 0, 0, 0);
    #pragma unroll
    for (int r = 0; r < 4; r++){
      s_sc[h][fg*4 + r][fr]      = s0[r] * SCORE_SCALE;
      s_sc[h][fg*4 + r][16 + fr] = s1[r] * SCORE_SCALE;
    }
    __syncthreads();

    // ---- structural bias, all heads cooperatively: thread <-> (il, jl) ----
    {
      int il = tid >> 5, jl = tid & 31;
      int i = i0 + il, j = j0 + jl;
      float spv = pos[(size_t)i*NN + j];
      int bkt;
      if (spv == 0.f) bkt = 0;
      else if (spv > 1.f) bkt = 11;
      else { float cc = spv * 10.f; cc = fminf(fmaxf(cc, 1.f), 10.f); bkt = (int)cc; }
      bool dg = (i == j);
      #pragma unroll
      for (int h2 = 0; h2 < 8; h2++){
        float add = s_spd[bkt*8 + h2];
        if (dg) add += s_slb[h2];
        s_sc[h2][il][jl] += add;
      }
    }
    __syncthreads();
    // ---- edge bias scatter (LDS atomics) ----
    for (int ix = tid; ix < ne; ix += 512){
      u32 me = s_em[ix];
      int dstn = (me >> 12) & 0xFFF;
      if (dstn >= j0 && dstn < j0 + 32){
        int ile = (int)(me & 0xFFF) - i0;
        int jle = dstn - j0;
        int tp = me >> 24;
        float wv = 200.f * s_ew[ix];
        #pragma unroll
        for (int h2 = 0; h2 < 8; h2++)
          atomicAdd(&s_sc[h2][ile][jle], s_ett[tp*8 + h2] + wv);
      }
    }
    __syncthreads();

    // ---- online softmax (wave h on its own plane; 4 lanes per row) ----
    float v8[8];
    #pragma unroll
    for (int c = 0; c < 8; c++) v8[c] = s_sc[h][sr][sg*8 + c];
    float mx = v8[0];
    #pragma unroll
    for (int c = 1; c < 8; c++) mx = fmaxf(mx, v8[c]);
    mx = fmaxf(mx, __shfl_xor(mx, 1));
    mx = fmaxf(mx, __shfl_xor(mx, 2));
    float mnew = fmaxf(m_run, mx);
    float fac = __expf(m_run - mnew);
    float psum = 0.f;
    union { u16 a[8]; bf16x8 v; } pu;
    #pragma unroll
    for (int c = 0; c < 8; c++){
      float pv = __expf(v8[c] - mnew);
      psum += pv;
      pu.a[c] = f2bf(pv);
    }
    psum += __shfl_xor(psum, 1);
    psum += __shfl_xor(psum, 2);
    l_run = l_run * fac + psum;
    m_run = mnew;
    if (sg == 0) s_fac[h][sr] = fac;
    *(bf16x8*)&s_p[h][sr][sg*8] = pu.v;
    __syncthreads();

    // ---- rescale accumulators, then PV ----
    #pragma unroll
    for (int r = 0; r < 4; r++){
      float fc = s_fac[h][fg*4 + r];
      o0[r] *= fc;
      o1[r] *= fc;
    }
    bf16x8 pa  = *(const bf16x8*)&s_p[h][fr][fg*8];
    bf16x8 vf0 = *(const bf16x8*)&vT[(size_t)(h*HDIM + fr)*NN + j0 + fg*8];
    bf16x8 vf1 = *(const bf16x8*)&vT[(size_t)(h*HDIM + 16 + fr)*NN + j0 + fg*8];
    o0 = MFMA16(pa, vf0, o0, 0, 0, 0);
    o1 = MFMA16(pa, vf1, o1, 0, 0, 0);
  }

  __syncthreads();
  if (sg == 0) s_fac[h][sr] = l_run;
  __syncthreads();
  #pragma unroll
  for (int r = 0; r < 4; r++){
    float linv = 1.f / s_fac[h][fg*4 + r];
    size_t row = i0 + fg*4 + r;
    aob[row*DM + h*HDIM + fr]      = f2bf(o0[r] * linv);
    aob[row*DM + h*HDIM + 16 + fr] = f2bf(o1[r] * linv);
  }
}

// ---------------- launcher ----------------
extern "C" void kernel_launch(void* const* d_in, const int* in_sizes, int n_in,
                              void* d_out, int out_size, void* d_ws, size_t ws_size,
                              hipStream_t stream){
  const float* x     = (const float*)d_in[0];
  const int*   ei    = (const int*)d_in[1];
  const int*   etyp  = (const int*)d_in[2];
  const float* pos   = (const float*)d_in[3];
  const float* ewin  = (const float*)d_in[4];
  const float* Wq    = (const float*)d_in[5];
  const float* bq    = (const float*)d_in[6];
  const float* Wk    = (const float*)d_in[7];
  const float* bk    = (const float*)d_in[8];
  const float* Wv    = (const float*)d_in[9];
  const float* bv    = (const float*)d_in[10];
  const float* Wo    = (const float*)d_in[11];
  const float* bo    = (const float*)d_in[12];
  const float* spd   = (const float*)d_in[13];
  const float* ett   = (const float*)d_in[14];
  const float* slb   = (const float*)d_in[15];
  const float* inde  = (const float*)d_in[16];
  const float* outde = (const float*)d_in[17];
  const float* dsc   = (const float*)d_in[18];
  const float* ln1g  = (const float*)d_in[19];
  const float* ln1b  = (const float*)d_in[20];
  const float* ln2g  = (const float*)d_in[21];
  const float* ln2b  = (const float*)d_in[22];
  const float* W1    = (const float*)d_in[23];
  const float* b1    = (const float*)d_in[24];
  const float* W2    = (const float*)d_in[25];
  const float* b2    = (const float*)d_in[26];
  const int* src = ei;
  const int* dst = ei + NE;

  char* p = (char*)d_ws;
  auto alloc = [&](size_t bytes) -> void* {
    void* r = (void*)p;
    p += (bytes + 255) & ~(size_t)255;
    return r;
  };
  int*  deg_in  = (int*)alloc(NN*4);
  int*  deg_out = (int*)alloc(NN*4);
  int*  fill    = (int*)alloc(NN*4);
  int*  row_ptr = (int*)alloc((NN+1)*4);
  u32*  emeta   = (u32*)alloc(NE*4);
  float* ewg    = (float*)alloc(NE*4);
  float* xb     = (float*)alloc((size_t)NN*DM*4);
  float* x2     = (float*)alloc((size_t)NN*DM*4);
  u16*  xnb     = (u16*)alloc((size_t)NN*DM*2);
  u16*  x2nb    = (u16*)alloc((size_t)NN*DM*2);
  u16*  qb      = (u16*)alloc((size_t)NN*DM*2);
  u16*  kb      = (u16*)alloc((size_t)NN*DM*2);
  u16*  vT      = (u16*)alloc((size_t)NN*DM*2);
  u16*  aob     = (u16*)alloc((size_t)NN*DM*2);
  u16*  h1b     = (u16*)alloc((size_t)NN*DFF*2);
  u16*  Wqt     = (u16*)alloc(65536*2);
  u16*  Wkt     = (u16*)alloc(65536*2);
  u16*  Wvt     = (u16*)alloc(65536*2);
  u16*  Wot     = (u16*)alloc(65536*2);
  u16*  W1t     = (u16*)alloc(262144*2);
  u16*  W2t     = (u16*)alloc(262144*2);

  // zero deg_in, deg_out, fill (contiguous, each padded to 12288 = mult of 256)
  hipMemsetAsync(deg_in, 0, 3*NN*4, stream);

  k_deg<<<NE/256, 256, 0, stream>>>(src, dst, deg_out, deg_in);
  k_scan<<<1, 1024, 0, stream>>>(deg_out, row_ptr);
  k_scatter<<<NE/256, 256, 0, stream>>>(src, dst, etyp, ewin, row_ptr, fill, emeta, ewg);
  k_conv<<<786432/256, 256, 0, stream>>>(Wq, Wk, Wv, Wo, W1, W2, Wqt, Wkt, Wvt, Wot, W1t, W2t);
  k_ln<<<NN, 256, 0, stream>>>(x, deg_in, deg_out, inde, outde, dsc, ln1g, ln1b, xb, xnb);

  dim3 g256(DM/64, NN/64);
  k_gemm<<<g256, 256, 0, stream>>>(xnb, Wqt, bq, nullptr, qb, DM, DM, 0);
  k_gemm<<<g256, 256, 0, stream>>>(xnb, Wkt, bk, nullptr, kb, DM, DM, 0);
  k_gemm<<<g256, 256, 0, stream>>>(xnb, Wvt, bv, nullptr, vT, DM, DM, 1);

  k_attn<<<NN/16, 512, 0, stream>>>(qb, kb, vT, pos, spd, ett, slb, emeta, ewg, row_ptr, aob);

  k_gemm<<<g256, 256, 0, stream>>>(aob, Wot, bo, xb, x2, DM, DM, 2);
  k_ln<<<NN, 256, 0, stream>>>(x2, nullptr, nullptr, nullptr, nullptr, nullptr, ln2g, ln2b, nullptr, x2nb);
  dim3 gffn1(DFF/64, NN/64);
  k_gemm<<<gffn1, 256, 0, stream>>>(x2nb, W1t, b1, nullptr, h1b, DM, DFF, 3);
  k_gemm<<<g256, 256, 0, stream>>>(h1b, W2t, b2, x2, d_out, DFF, DM, 4);
}

// Round 4
// 327.779 us; speedup vs baseline: 1.4377x; 1.4377x over previous
//
#include <hip/hip_runtime.h>
#include <hip/hip_bf16.h>

#define NN 3072
#define DM 256
#define NH 8
#define HDIM 32
#define NE 98304
#define DFF 1024
#define MAXDEG 512
#define NIT 192   // NN/16 i-tiles
#define NJT 48    // NN/64 j-tiles
#define JSPLIT 2

typedef short bf16x8 __attribute__((ext_vector_type(8)));
typedef float f32x4 __attribute__((ext_vector_type(4)));
typedef unsigned short u16;
typedef unsigned int u32;

#define MFMA16 __builtin_amdgcn_mfma_f32_16x16x32_bf16

__device__ __forceinline__ u16 f2bf(float f){
  u32 u = __builtin_bit_cast(u32, f);
  u32 r = (u + 0x7FFFu + ((u >> 16) & 1u)) >> 16;
  return (u16)r;
}

// ---------------- degree + bucket count ----------------
__global__ void k_deg(const int* __restrict__ src, const int* __restrict__ dst,
                      int* __restrict__ deg_out, int* __restrict__ deg_in,
                      int* __restrict__ bcnt){
  int e = blockIdx.x * 256 + threadIdx.x;
  if (e < NE){
    int s = src[e], d = dst[e];
    atomicAdd(&deg_out[s], 1);
    atomicAdd(&deg_in[d], 1);
    atomicAdd(&bcnt[(s >> 4) * NJT + (d >> 6)], 1);
  }
}

// ---------------- exclusive scan of bcnt[9216] -> bptr[9217] ----------------
__global__ __launch_bounds__(1024)
void k_scan(const int* __restrict__ cnt, int* __restrict__ ptr){
  __shared__ int sc[1024];
  int t = threadIdx.x;
  int loc[9]; int s = 0;
  #pragma unroll
  for (int u = 0; u < 9; u++){ loc[u] = cnt[t*9 + u]; s += loc[u]; }
  sc[t] = s;
  __syncthreads();
  for (int off = 1; off < 1024; off <<= 1){
    int v = (t >= off) ? sc[t-off] : 0;
    __syncthreads();
    sc[t] += v;
    __syncthreads();
  }
  int run = sc[t] - s;
  #pragma unroll
  for (int u = 0; u < 9; u++){ ptr[t*9 + u] = run; run += loc[u]; }
  if (t == 1023) ptr[9216] = run;
}

// ---------------- scatter edges into (i-tile, j-tile) buckets ----------------
__global__ void k_scatter(const int* __restrict__ src, const int* __restrict__ dst,
                          const int* __restrict__ types, const float* __restrict__ w,
                          const int* __restrict__ bptr, int* __restrict__ bfill,
                          u16* __restrict__ meta, float* __restrict__ ews){
  int e = blockIdx.x * 256 + threadIdx.x;
  if (e < NE){
    int s = src[e], d = dst[e];
    int b = (s >> 4) * NJT + (d >> 6);
    int slot = bptr[b] + atomicAdd(&bfill[b], 1);
    meta[slot] = (u16)((s & 15) | ((d & 63) << 4) | (types[e] << 10));
    ews[slot] = w[e];
  }
}

// ---------------- pos -> permuted u8 bucket array ----------------
// bktP[i][ (j&~63) + (j&15)*4 + ((j>>4)&3) ] = bucket(pos[i][j])
__global__ __launch_bounds__(1024)
void k_bucket(const float* __restrict__ pos, unsigned char* __restrict__ bktP){
  int j = blockIdx.x * 1024 + threadIdx.x;
  int i = blockIdx.y;
  float spv = pos[(size_t)i*NN + j];
  int bkt;
  if (spv == 0.f) bkt = 0;
  else if (spv > 1.f) bkt = 11;
  else { float cc = fminf(fmaxf(spv * 10.f, 1.f), 10.f); bkt = (int)cc; }
  bktP[(size_t)i*NN + (j & ~63) + (j & 15)*4 + ((j >> 4) & 3)] = (unsigned char)bkt;
}

// ---------------- LDS-tiled weight transpose + bf16 convert ----------------
__global__ __launch_bounds__(256)
void k_trans(const float* __restrict__ Wq, const float* __restrict__ Wk,
             const float* __restrict__ Wv, const float* __restrict__ Wo,
             const float* __restrict__ W1, const float* __restrict__ W2,
             u16* __restrict__ Wqkvot, u16* __restrict__ W1t, u16* __restrict__ W2t){
  __shared__ u16 t_[32][33];
  int bt = blockIdx.x;   // 0..767
  const float* srcm; u16* dstm; int K, N, kt, nt;
  if (bt < 256){
    int m = bt >> 6, r = bt & 63; kt = r >> 3; nt = r & 7; K = 256; N = 256;
    srcm = (m==0)?Wq:(m==1)?Wk:(m==2)?Wv:Wo; dstm = Wqkvot + m*65536;
  } else if (bt < 512){
    int r = bt - 256; kt = r >> 5; nt = r & 31; K = 256; N = 1024; srcm = W1; dstm = W1t;
  } else {
    int r = bt - 512; kt = r >> 3; nt = r & 7; K = 1024; N = 256; srcm = W2; dstm = W2t;
  }
  int tx = threadIdx.x & 31, ty = threadIdx.x >> 5;
  #pragma unroll
  for (int s = 0; s < 4; s++)
    t_[ty + 8*s][tx] = f2bf(srcm[(size_t)(kt*32 + ty + 8*s)*N + nt*32 + tx]);
  __syncthreads();
  #pragma unroll
  for (int s = 0; s < 4; s++)
    dstm[(size_t)(nt*32 + ty + 8*s)*K + kt*32 + tx] = t_[tx][ty + 8*s];
}

// ---------------- LayerNorm (optionally fused degree-embedding add) ----------------
__global__ __launch_bounds__(256)
void k_ln(const float* __restrict__ in, const int* __restrict__ deg_in,
          const int* __restrict__ deg_out, const float* __restrict__ in_emb,
          const float* __restrict__ out_emb, const float* __restrict__ dscale,
          const float* __restrict__ g, const float* __restrict__ b,
          float* __restrict__ save_f32, u16* __restrict__ out_bf){
  int i = blockIdx.x, c = threadIdx.x;
  size_t idx = (size_t)i*DM + c;
  float val = in[idx];
  if (deg_in){
    int di = min(deg_in[i], MAXDEG), dg = min(deg_out[i], MAXDEG);
    val += (in_emb[(size_t)di*DM + c] + out_emb[(size_t)dg*DM + c]) * dscale[0];
    save_f32[idx] = val;
  }
  float s = val, s2 = val*val;
  #pragma unroll
  for (int off = 32; off; off >>= 1){
    s  += __shfl_xor(s, off);
    s2 += __shfl_xor(s2, off);
  }
  __shared__ float red[8];
  int lane = c & 63, w = c >> 6;
  if (lane == 0){ red[w] = s; red[4+w] = s2; }
  __syncthreads();
  s  = red[0] + red[1] + red[2] + red[3];
  s2 = red[4] + red[5] + red[6] + red[7];
  float mean = s * (1.f/256.f);
  float var = s2 * (1.f/256.f) - mean*mean;
  float xn = (val - mean) * rsqrtf(var + 1e-5f) * g[c] + b[c];
  out_bf[idx] = f2bf(xn);
}

// ---------------- generic MFMA GEMM: C = A[M][K] * Bt[N][K]^T ----------------
// mode 5: QKV split epilogue (b0/b1/b2 biases; out=qb base u16, out2=vT u16)
// mode 2: f32 out = res + val (bias b0)
// mode 3: u16 out = bf16(gelu(val)) (bias b0)
__global__ __launch_bounds__(256)
void k_gemm(const u16* __restrict__ A, const u16* __restrict__ Bt,
            const float* __restrict__ b0, const float* __restrict__ b1,
            const float* __restrict__ b2, const float* __restrict__ res,
            void* __restrict__ out, void* __restrict__ out2,
            int K, int Ncols, int mode){
  __shared__ u16 sA[64][40];
  __shared__ u16 sB[64][40];
  const int tid = threadIdx.x, lane = tid & 63, wid = tid >> 6;
  const int m0 = blockIdx.y * 64, n0 = blockIdx.x * 64;
  const int wr = (wid >> 1) * 32, wc = (wid & 1) * 32;
  const int srow = tid >> 2, scol = (tid & 3) * 8;
  const int fr = lane & 15, fg = lane >> 4;
  f32x4 acc00 = {0,0,0,0}, acc01 = {0,0,0,0}, acc10 = {0,0,0,0}, acc11 = {0,0,0,0};
  for (int k0 = 0; k0 < K; k0 += 32){
    __syncthreads();
    *(bf16x8*)&sA[srow][scol] = *(const bf16x8*)&A[(size_t)(m0+srow)*K + k0 + scol];
    *(bf16x8*)&sB[srow][scol] = *(const bf16x8*)&Bt[(size_t)(n0+srow)*K + k0 + scol];
    __syncthreads();
    bf16x8 a0 = *(const bf16x8*)&sA[wr + fr][fg*8];
    bf16x8 a1 = *(const bf16x8*)&sA[wr + 16 + fr][fg*8];
    bf16x8 b0f = *(const bf16x8*)&sB[wc + fr][fg*8];
    bf16x8 b1f = *(const bf16x8*)&sB[wc + 16 + fr][fg*8];
    acc00 = MFMA16(a0, b0f, acc00, 0, 0, 0);
    acc01 = MFMA16(a0, b1f, acc01, 0, 0, 0);
    acc10 = MFMA16(a1, b0f, acc10, 0, 0, 0);
    acc11 = MFMA16(a1, b1f, acc11, 0, 0, 0);
  }
  #pragma unroll
  for (int fm = 0; fm < 2; fm++)
  #pragma unroll
  for (int fn = 0; fn < 2; fn++){
    f32x4 c = (fm==0) ? ((fn==0) ? acc00 : acc01) : ((fn==0) ? acc10 : acc11);
    #pragma unroll
    for (int r = 0; r < 4; r++){
      int row = m0 + wr + fm*16 + fg*4 + r;
      int col = n0 + wc + fn*16 + fr;
      if (mode == 5){
        int seg = col >> 8, cn = col & 255;
        const float* bp = (seg==0) ? b0 : (seg==1) ? b1 : b2;
        float val = c[r] + bp[cn];
        if (seg < 2) ((u16*)out)[(size_t)seg*NN*DM + (size_t)row*DM + cn] = f2bf(val);
        else         ((u16*)out2)[(size_t)cn*NN + row] = f2bf(val);
      } else {
        float val = c[r] + b0[col];
        size_t idx = (size_t)row*Ncols + col;
        if (mode == 2) ((float*)out)[idx] = res[idx] + val;
        else           ((u16*)out)[idx] = f2bf(0.5f*val*(1.f + erff(val*0.70710678f)));
      }
    }
  }
}

// ---------------- barrier-free per-wave fused attention ----------------
// WG = 512 = 8 waves; wave h = head h for 16 q-rows; grid (192 i-tiles, JSPLIT j-chunks).
__global__ __launch_bounds__(512)
void k_attn(const u16* __restrict__ qb, const u16* __restrict__ kb, const u16* __restrict__ vT,
            const unsigned char* __restrict__ bktP,
            const float* __restrict__ spd_table, const float* __restrict__ slb,
            const u16* __restrict__ meta, const float* __restrict__ ews,
            const float* __restrict__ ett, const int* __restrict__ bptr,
            float* __restrict__ opart, float* __restrict__ mpart, float* __restrict__ lpart){
  __shared__ float s_spd[96];
  __shared__ float s_ett[128];
  __shared__ float s_sc[NH][16][68];
  const int tid = threadIdx.x, lane = tid & 63, h = tid >> 6;
  const int it = blockIdx.x, jc = blockIdx.y;
  const int i0 = it * 16;
  const float SCALE = 0.70710678f;   // 1/(0.25*sqrt(32))
  if (tid < 96) s_spd[tid] = spd_table[tid] * 10.f;
  else if (tid >= 128 && tid < 256) s_ett[tid-128] = ett[tid-128] * 10.f;
  const float slbh = slb[h];
  const int fr = lane & 15, fg = lane >> 4;
  bf16x8 qv = *(const bf16x8*)&qb[(size_t)(i0 + fr)*DM + h*HDIM + fg*8];
  float (*sc)[68] = s_sc[h];
  f32x4 o0 = {0,0,0,0}, o1 = {0,0,0,0};
  float m_run = -3.0e38f, l_run = 0.f;
  __syncthreads();

  for (int jt = jc*(NJT/JSPLIT); jt < (jc+1)*(NJT/JSPLIT); ++jt){
    const int j0 = jt * 64;
    // ---- loads ----
    bf16x8 kf0 = *(const bf16x8*)&kb[(size_t)(j0      + fr)*DM + h*HDIM + fg*8];
    bf16x8 kf1 = *(const bf16x8*)&kb[(size_t)(j0 + 16 + fr)*DM + h*HDIM + fg*8];
    bf16x8 kf2 = *(const bf16x8*)&kb[(size_t)(j0 + 32 + fr)*DM + h*HDIM + fg*8];
    bf16x8 kf3 = *(const bf16x8*)&kb[(size_t)(j0 + 48 + fr)*DM + h*HDIM + fg*8];
    uchar4 bk0 = *(const uchar4*)&bktP[(size_t)(i0 + fg*4 + 0)*NN + j0 + fr*4];
    uchar4 bk1 = *(const uchar4*)&bktP[(size_t)(i0 + fg*4 + 1)*NN + j0 + fr*4];
    uchar4 bk2 = *(const uchar4*)&bktP[(size_t)(i0 + fg*4 + 2)*NN + j0 + fr*4];
    uchar4 bk3 = *(const uchar4*)&bktP[(size_t)(i0 + fg*4 + 3)*NN + j0 + fr*4];
    // ---- QK^T ----
    f32x4 z = {0,0,0,0};
    f32x4 s0 = MFMA16(qv, kf0, z, 0, 0, 0);
    f32x4 s1 = MFMA16(qv, kf1, z, 0, 0, 0);
    f32x4 s2 = MFMA16(qv, kf2, z, 0, 0, 0);
    f32x4 s3 = MFMA16(qv, kf3, z, 0, 0, 0);
    // ---- write scores + spd/diag bias to wave-private LDS plane ----
    unsigned char bb[4][4] = {{bk0.x,bk0.y,bk0.z,bk0.w},{bk1.x,bk1.y,bk1.z,bk1.w},
                              {bk2.x,bk2.y,bk2.z,bk2.w},{bk3.x,bk3.y,bk3.z,bk3.w}};
    #pragma unroll
    for (int r = 0; r < 4; r++){
      int row = fg*4 + r;
      #pragma unroll
      for (int c2 = 0; c2 < 4; c2++){
        int col = c2*16 + fr;
        float sv = (c2==0) ? s0[r] : (c2==1) ? s1[r] : (c2==2) ? s2[r] : s3[r];
        float val = sv * SCALE + s_spd[(int)bb[r][c2]*8 + h];
        if (i0 + row == j0 + col) val += slbh;
        sc[row][col] = val;
      }
    }
    // ---- edge bias: one LDS atomic per edge (wave-private plane) ----
    {
      int e0 = bptr[it*NJT + jt], e1 = bptr[it*NJT + jt + 1];
      for (int ix = e0 + lane; ix < e1; ix += 64){
        u16 me = meta[ix];
        int il = me & 15, jl = (me >> 4) & 63, tp = me >> 10;
        atomicAdd(&sc[il][jl], s_ett[tp*8 + h] + 200.f * ews[ix]);
      }
    }
    // ---- read back in A-fragment layout (row fr, cols fg*8.. & 32+fg*8..) ----
    float v[16];
    { f32x4 a = *(const f32x4*)&sc[fr][fg*8];
      v[0]=a[0]; v[1]=a[1]; v[2]=a[2]; v[3]=a[3]; }
    { f32x4 a = *(const f32x4*)&sc[fr][fg*8 + 4];
      v[4]=a[0]; v[5]=a[1]; v[6]=a[2]; v[7]=a[3]; }
    { f32x4 a = *(const f32x4*)&sc[fr][32 + fg*8];
      v[8]=a[0]; v[9]=a[1]; v[10]=a[2]; v[11]=a[3]; }
    { f32x4 a = *(const f32x4*)&sc[fr][32 + fg*8 + 4];
      v[12]=a[0]; v[13]=a[1]; v[14]=a[2]; v[15]=a[3]; }
    // ---- online softmax (row fr; 4 replicas across fg) ----
    float mx = v[0];
    #pragma unroll
    for (int t = 1; t < 16; t++) mx = fmaxf(mx, v[t]);
    mx = fmaxf(mx, __shfl_xor(mx, 16));
    mx = fmaxf(mx, __shfl_xor(mx, 32));
    float mnew = fmaxf(m_run, mx);
    float fac = __expf(m_run - mnew);
    float p[16], ps = 0.f;
    #pragma unroll
    for (int t = 0; t < 16; t++){ p[t] = __expf(v[t] - mnew); ps += p[t]; }
    ps += __shfl_xor(ps, 16);
    ps += __shfl_xor(ps, 32);
    l_run = l_run * fac + ps;
    m_run = mnew;
    // ---- redistribute fac to accumulator rows (fg*4+r), rescale ----
    float f0 = __shfl(fac, fg*4 + 0);
    float f1 = __shfl(fac, fg*4 + 1);
    float f2 = __shfl(fac, fg*4 + 2);
    float f3 = __shfl(fac, fg*4 + 3);
    o0[0]*=f0; o0[1]*=f1; o0[2]*=f2; o0[3]*=f3;
    o1[0]*=f0; o1[1]*=f1; o1[2]*=f2; o1[3]*=f3;
    // ---- P (in regs already in A-frag layout) -> bf16, PV ----
    union { u16 a[8]; bf16x8 v8; } pa0u, pa1u;
    #pragma unroll
    for (int t = 0; t < 8; t++){ pa0u.a[t] = f2bf(p[t]); pa1u.a[t] = f2bf(p[8+t]); }
    bf16x8 vf00 = *(const bf16x8*)&vT[(size_t)(h*HDIM      + fr)*NN + j0      + fg*8];
    bf16x8 vf01 = *(const bf16x8*)&vT[(size_t)(h*HDIM      + fr)*NN + j0 + 32 + fg*8];
    bf16x8 vf10 = *(const bf16x8*)&vT[(size_t)(h*HDIM + 16 + fr)*NN + j0      + fg*8];
    bf16x8 vf11 = *(const bf16x8*)&vT[(size_t)(h*HDIM + 16 + fr)*NN + j0 + 32 + fg*8];
    o0 = MFMA16(pa0u.v8, vf00, o0, 0, 0, 0);
    o0 = MFMA16(pa1u.v8, vf01, o0, 0, 0, 0);
    o1 = MFMA16(pa0u.v8, vf10, o1, 0, 0, 0);
    o1 = MFMA16(pa1u.v8, vf11, o1, 0, 0, 0);
  }

  // ---- write unnormalized partials ----
  float* ob = opart + (size_t)jc*NN*DM;
  #pragma unroll
  for (int r = 0; r < 4; r++){
    size_t row = i0 + fg*4 + r;
    ob[row*DM + h*HDIM + fr]      = o0[r];
    ob[row*DM + h*HDIM + 16 + fr] = o1[r];
  }
  if (fg == 0){
    mpart[jc*NN*NH + (i0 + fr)*NH + h] = m_run;
    lpart[jc*NN*NH + (i0 + fr)*NH + h] = l_run;
  }
}

// ---------------- combine J-split partials ----------------
__global__ __launch_bounds__(256)
void k_reduce(const float* __restrict__ opart, const float* __restrict__ mpart,
              const float* __restrict__ lpart, u16* __restrict__ aob){
  int row = blockIdx.x, col = threadIdx.x, h = col >> 5;
  float m0 = mpart[row*NH + h], m1 = mpart[NN*NH + row*NH + h];
  float l0 = lpart[row*NH + h], l1 = lpart[NN*NH + row*NH + h];
  float M = fmaxf(m0, m1);
  float w0 = __expf(m0 - M), w1 = __expf(m1 - M);
  float L = l0*w0 + l1*w1;
  float a = opart[(size_t)row*DM + col], b = opart[(size_t)NN*DM + (size_t)row*DM + col];
  aob[(size_t)row*DM + col] = f2bf((a*w0 + b*w1) / L);
}

// ---------------- launcher ----------------
extern "C" void kernel_launch(void* const* d_in, const int* in_sizes, int n_in,
                              void* d_out, int out_size, void* d_ws, size_t ws_size,
                              hipStream_t stream){
  const float* x     = (const float*)d_in[0];
  const int*   ei    = (const int*)d_in[1];
  const int*   etyp  = (const int*)d_in[2];
  const float* pos   = (const float*)d_in[3];
  const float* ewin  = (const float*)d_in[4];
  const float* Wq    = (const float*)d_in[5];
  const float* bq    = (const float*)d_in[6];
  const float* Wk    = (const float*)d_in[7];
  const float* bk    = (const float*)d_in[8];
  const float* Wv    = (const float*)d_in[9];
  const float* bv    = (const float*)d_in[10];
  const float* Wo    = (const float*)d_in[11];
  const float* bo    = (const float*)d_in[12];
  const float* spd   = (const float*)d_in[13];
  const float* ett   = (const float*)d_in[14];
  const float* slb   = (const float*)d_in[15];
  const float* inde  = (const float*)d_in[16];
  const float* outde = (const float*)d_in[17];
  const float* dsc   = (const float*)d_in[18];
  const float* ln1g  = (const float*)d_in[19];
  const float* ln1b  = (const float*)d_in[20];
  const float* ln2g  = (const float*)d_in[21];
  const float* ln2b  = (const float*)d_in[22];
  const float* W1    = (const float*)d_in[23];
  const float* b1    = (const float*)d_in[24];
  const float* W2    = (const float*)d_in[25];
  const float* b2    = (const float*)d_in[26];
  const int* src = ei;
  const int* dst = ei + NE;

  char* p = (char*)d_ws;
  auto alloc = [&](size_t bytes) -> void* {
    void* r = (void*)p;
    p += (bytes + 255) & ~(size_t)255;
    return r;
  };
  // zeroed region (contiguous): deg_in, deg_out, bcnt, bfill
  int*  deg_in  = (int*)alloc(NN*4);
  int*  deg_out = (int*)alloc(NN*4);
  int*  bcnt    = (int*)alloc(9216*4);
  int*  bfill   = (int*)alloc(9216*4);
  int*  bptr    = (int*)alloc(9217*4);
  u16*  meta    = (u16*)alloc(NE*2);
  float* ews    = (float*)alloc(NE*4);
  unsigned char* bktP = (unsigned char*)alloc((size_t)NN*NN);
  float* xb     = (float*)alloc((size_t)NN*DM*4);
  float* x2     = (float*)alloc((size_t)NN*DM*4);
  u16*  xnb     = (u16*)alloc((size_t)NN*DM*2);
  u16*  x2nb    = (u16*)alloc((size_t)NN*DM*2);
  u16*  qb      = (u16*)alloc((size_t)NN*DM*2);   // qb, kb contiguous
  u16*  kb      = (u16*)alloc((size_t)NN*DM*2);
  u16*  vT      = (u16*)alloc((size_t)NN*DM*2);
  u16*  aob     = (u16*)alloc((size_t)NN*DM*2);
  u16*  h1b     = (u16*)alloc((size_t)NN*DFF*2);
  float* opart  = (float*)alloc((size_t)JSPLIT*NN*DM*4);
  float* mpart  = (float*)alloc((size_t)JSPLIT*NN*NH*4);
  float* lpart  = (float*)alloc((size_t)JSPLIT*NN*NH*4);
  u16*  Wqkvot  = (u16*)alloc(4*65536*2);          // Wq^T,Wk^T,Wv^T,Wo^T contiguous
  u16*  W1t     = (u16*)alloc(262144*2);
  u16*  W2t     = (u16*)alloc(262144*2);
  (void)kb;

  hipMemsetAsync(deg_in, 0, (2*NN + 2*9216)*4, stream);

  k_deg<<<NE/256, 256, 0, stream>>>(src, dst, deg_out, deg_in, bcnt);
  k_scan<<<1, 1024, 0, stream>>>(bcnt, bptr);
  k_scatter<<<NE/256, 256, 0, stream>>>(src, dst, etyp, ewin, bptr, bfill, meta, ews);
  k_bucket<<<dim3(3, NN), 1024, 0, stream>>>(pos, bktP);
  k_trans<<<768, 256, 0, stream>>>(Wq, Wk, Wv, Wo, W1, W2, Wqkvot, W1t, W2t);
  k_ln<<<NN, 256, 0, stream>>>(x, deg_in, deg_out, inde, outde, dsc, ln1g, ln1b, xb, xnb);

  // fused QKV: Bt = [Wq^T; Wk^T; Wv^T] (768 x 256)
  k_gemm<<<dim3(12, 48), 256, 0, stream>>>(xnb, Wqkvot, bq, bk, bv, nullptr,
                                           qb, vT, DM, 768, 5);

  k_attn<<<dim3(NIT, JSPLIT), 512, 0, stream>>>(qb, kb, vT, bktP, spd, slb, meta, ews,
                                                ett, bptr, opart, mpart, lpart);
  k_reduce<<<NN, 256, 0, stream>>>(opart, mpart, lpart, aob);

  u16* Wot = Wqkvot + 3*65536;
  k_gemm<<<dim3(4, 48), 256, 0, stream>>>(aob, Wot, bo, nullptr, nullptr, xb,
                                          x2, nullptr, DM, DM, 2);
  k_ln<<<NN, 256, 0, stream>>>(x2, nullptr, nullptr, nullptr, nullptr, nullptr,
                               ln2g, ln2b, nullptr, x2nb);
  k_gemm<<<dim3(16, 48), 256, 0, stream>>>(x2nb, W1t, b1, nullptr, nullptr, nullptr,
                                           h1b, nullptr, DM, DFF, 3);
  k_gemm<<<dim3(4, 48), 256, 0, stream>>>(h1b, W2t, b2, nullptr, nullptr, x2,
                                          d_out, nullptr, DFF, DM, 2);
}

// Round 9
// 313.876 us; speedup vs baseline: 1.5014x; 1.0443x over previous
//
#include <hip/hip_runtime.h>
#include <hip/hip_bf16.h>

#define NN 3072
#define DM 256
#define NH 8
#define HDIM 32
#define NE 98304
#define DFF 1024
#define MAXDEG 512
#define NIT 192   // NN/16 i-tiles
#define NJT 48    // NN/64 j-tiles
#define JSPLIT 4

typedef short bf16x8 __attribute__((ext_vector_type(8)));
typedef float f32x4 __attribute__((ext_vector_type(4)));
typedef unsigned short u16;
typedef unsigned int u32;

#define MFMA16 __builtin_amdgcn_mfma_f32_16x16x32_bf16

__device__ __forceinline__ u16 f2bf(float f){
  u32 u = __builtin_bit_cast(u32, f);
  u32 r = (u + 0x7FFFu + ((u >> 16) & 1u)) >> 16;
  return (u16)r;
}
__device__ __forceinline__ u32 cvtpk(float lo, float hi){
  u32 r; asm("v_cvt_pk_bf16_f32 %0, %1, %2" : "=v"(r) : "v"(lo), "v"(hi)); return r;
}

// ---------------- degree + bucket count ----------------
__global__ void k_deg(const int* __restrict__ src, const int* __restrict__ dst,
                      int* __restrict__ deg_out, int* __restrict__ deg_in,
                      int* __restrict__ bcnt){
  int e = blockIdx.x * 256 + threadIdx.x;
  if (e < NE){
    int s = src[e], d = dst[e];
    atomicAdd(&deg_out[s], 1);
    atomicAdd(&deg_in[d], 1);
    atomicAdd(&bcnt[(s >> 4) * NJT + (d >> 6)], 1);
  }
}

// ---------------- exclusive scan of bcnt[9216] -> bptr[9217] ----------------
__global__ __launch_bounds__(1024)
void k_scan(const int* __restrict__ cnt, int* __restrict__ ptr){
  __shared__ int sc[1024];
  int t = threadIdx.x;
  int loc[9]; int s = 0;
  #pragma unroll
  for (int u = 0; u < 9; u++){ loc[u] = cnt[t*9 + u]; s += loc[u]; }
  sc[t] = s;
  __syncthreads();
  for (int off = 1; off < 1024; off <<= 1){
    int v = (t >= off) ? sc[t-off] : 0;
    __syncthreads();
    sc[t] += v;
    __syncthreads();
  }
  int run = sc[t] - s;
  #pragma unroll
  for (int u = 0; u < 9; u++){ ptr[t*9 + u] = run; run += loc[u]; }
  if (t == 1023) ptr[9216] = run;
}

// ---------------- scatter edges into (i-tile, j-tile) buckets ----------------
__global__ void k_scatter(const int* __restrict__ src, const int* __restrict__ dst,
                          const int* __restrict__ types, const float* __restrict__ w,
                          const int* __restrict__ bptr, int* __restrict__ bfill,
                          u16* __restrict__ meta, float* __restrict__ ews){
  int e = blockIdx.x * 256 + threadIdx.x;
  if (e < NE){
    int s = src[e], d = dst[e];
    int b = (s >> 4) * NJT + (d >> 6);
    int slot = bptr[b] + atomicAdd(&bfill[b], 1);
    meta[slot] = (u16)((s & 15) | ((d & 63) << 4) | (types[e] << 10));
    ews[slot] = w[e];
  }
}

// ---------------- pos -> permuted u8 bucket array ----------------
// bktP[i][ (j&~63) + (j&15)*4 + ((j>>4)&3) ] = bucket(pos[i][j])
__global__ __launch_bounds__(1024)
void k_bucket(const float* __restrict__ pos, unsigned char* __restrict__ bktP){
  int j = blockIdx.x * 1024 + threadIdx.x;
  int i = blockIdx.y;
  float spv = pos[(size_t)i*NN + j];
  int bkt;
  if (spv == 0.f) bkt = 0;
  else if (spv > 1.f) bkt = 11;
  else { float cc = fminf(fmaxf(spv * 10.f, 1.f), 10.f); bkt = (int)cc; }
  bktP[(size_t)i*NN + (j & ~63) + (j & 15)*4 + ((j >> 4) & 3)] = (unsigned char)bkt;
}

// ---------------- LDS-tiled weight transpose + bf16 convert ----------------
__global__ __launch_bounds__(256)
void k_trans(const float* __restrict__ Wq, const float* __restrict__ Wk,
             const float* __restrict__ Wv, const float* __restrict__ Wo,
             const float* __restrict__ W1, const float* __restrict__ W2,
             u16* __restrict__ Wqkvot, u16* __restrict__ W1t, u16* __restrict__ W2t){
  __shared__ u16 t_[32][33];
  int bt = blockIdx.x;   // 0..767
  const float* srcm; u16* dstm; int K, N, kt, nt;
  if (bt < 256){
    int m = bt >> 6, r = bt & 63; kt = r >> 3; nt = r & 7; K = 256; N = 256;
    srcm = (m==0)?Wq:(m==1)?Wk:(m==2)?Wv:Wo; dstm = Wqkvot + m*65536;
  } else if (bt < 512){
    int r = bt - 256; kt = r >> 5; nt = r & 31; K = 256; N = 1024; srcm = W1; dstm = W1t;
  } else {
    int r = bt - 512; kt = r >> 3; nt = r & 7; K = 1024; N = 256; srcm = W2; dstm = W2t;
  }
  int tx = threadIdx.x & 31, ty = threadIdx.x >> 5;
  #pragma unroll
  for (int s = 0; s < 4; s++)
    t_[ty + 8*s][tx] = f2bf(srcm[(size_t)(kt*32 + ty + 8*s)*N + nt*32 + tx]);
  __syncthreads();
  #pragma unroll
  for (int s = 0; s < 4; s++)
    dstm[(size_t)(nt*32 + ty + 8*s)*K + kt*32 + tx] = t_[tx][ty + 8*s];
}

// ---------------- LayerNorm (optionally fused degree-embedding add) ----------------
__global__ __launch_bounds__(256)
void k_ln(const float* __restrict__ in, const int* __restrict__ deg_in,
          const int* __restrict__ deg_out, const float* __restrict__ in_emb,
          const float* __restrict__ out_emb, const float* __restrict__ dscale,
          const float* __restrict__ g, const float* __restrict__ b,
          float* __restrict__ save_f32, u16* __restrict__ out_bf){
  int i = blockIdx.x, c = threadIdx.x;
  size_t idx = (size_t)i*DM + c;
  float val = in[idx];
  if (deg_in){
    int di = min(deg_in[i], MAXDEG), dg = min(deg_out[i], MAXDEG);
    val += (in_emb[(size_t)di*DM + c] + out_emb[(size_t)dg*DM + c]) * dscale[0];
    save_f32[idx] = val;
  }
  float s = val, s2 = val*val;
  #pragma unroll
  for (int off = 32; off; off >>= 1){
    s  += __shfl_xor(s, off);
    s2 += __shfl_xor(s2, off);
  }
  __shared__ float red[8];
  int lane = c & 63, w = c >> 6;
  if (lane == 0){ red[w] = s; red[4+w] = s2; }
  __syncthreads();
  s  = red[0] + red[1] + red[2] + red[3];
  s2 = red[4] + red[5] + red[6] + red[7];
  float mean = s * (1.f/256.f);
  float var = s2 * (1.f/256.f) - mean*mean;
  float xn = (val - mean) * rsqrtf(var + 1e-5f) * g[c] + b[c];
  out_bf[idx] = f2bf(xn);
}

// ---------------- generic MFMA GEMM, BK=64: C = A[M][K] * Bt[N][K]^T ----------------
// mode 5: QKV split epilogue (b0/b1/b2 biases; Q gets *SCALE; out=qb, out2=vT)
// mode 2: f32 out = res + val (bias b0)
// mode 3: u16 out = bf16(gelu(val)) (bias b0)
__global__ __launch_bounds__(256)
void k_gemm(const u16* __restrict__ A, const u16* __restrict__ Bt,
            const float* __restrict__ b0, const float* __restrict__ b1,
            const float* __restrict__ b2, const float* __restrict__ res,
            void* __restrict__ out, void* __restrict__ out2,
            int K, int Ncols, int mode){
  __shared__ u16 sA[64][72];
  __shared__ u16 sB[64][72];
  const int tid = threadIdx.x, lane = tid & 63, wid = tid >> 6;
  const int m0 = blockIdx.y * 64, n0 = blockIdx.x * 64;
  const int wr = (wid >> 1) * 32, wc = (wid & 1) * 32;
  const int srow = tid >> 2, scol = (tid & 3) * 16;
  const int fr = lane & 15, fg = lane >> 4;
  f32x4 acc00 = {0,0,0,0}, acc01 = {0,0,0,0}, acc10 = {0,0,0,0}, acc11 = {0,0,0,0};
  for (int k0 = 0; k0 < K; k0 += 64){
    __syncthreads();
    *(bf16x8*)&sA[srow][scol]     = *(const bf16x8*)&A[(size_t)(m0+srow)*K + k0 + scol];
    *(bf16x8*)&sA[srow][scol + 8] = *(const bf16x8*)&A[(size_t)(m0+srow)*K + k0 + scol + 8];
    *(bf16x8*)&sB[srow][scol]     = *(const bf16x8*)&Bt[(size_t)(n0+srow)*K + k0 + scol];
    *(bf16x8*)&sB[srow][scol + 8] = *(const bf16x8*)&Bt[(size_t)(n0+srow)*K + k0 + scol + 8];
    __syncthreads();
    #pragma unroll
    for (int kk = 0; kk < 2; kk++){
      bf16x8 a0  = *(const bf16x8*)&sA[wr + fr][kk*32 + fg*8];
      bf16x8 a1  = *(const bf16x8*)&sA[wr + 16 + fr][kk*32 + fg*8];
      bf16x8 b0f = *(const bf16x8*)&sB[wc + fr][kk*32 + fg*8];
      bf16x8 b1f = *(const bf16x8*)&sB[wc + 16 + fr][kk*32 + fg*8];
      acc00 = MFMA16(a0, b0f, acc00, 0, 0, 0);
      acc01 = MFMA16(a0, b1f, acc01, 0, 0, 0);
      acc10 = MFMA16(a1, b0f, acc10, 0, 0, 0);
      acc11 = MFMA16(a1, b1f, acc11, 0, 0, 0);
    }
  }
  #pragma unroll
  for (int fm = 0; fm < 2; fm++)
  #pragma unroll
  for (int fn = 0; fn < 2; fn++){
    f32x4 c = (fm==0) ? ((fn==0) ? acc00 : acc01) : ((fn==0) ? acc10 : acc11);
    #pragma unroll
    for (int r = 0; r < 4; r++){
      int row = m0 + wr + fm*16 + fg*4 + r;
      int col = n0 + wc + fn*16 + fr;
      if (mode == 5){
        int seg = col >> 8, cn = col & 255;
        const float* bp = (seg==0) ? b0 : (seg==1) ? b1 : b2;
        float val = c[r] + bp[cn];
        if (seg == 0) val *= 0.70710678f;   // fold score scale into Q
        if (seg < 2) ((u16*)out)[(size_t)seg*NN*DM + (size_t)row*DM + cn] = f2bf(val);
        else         ((u16*)out2)[(size_t)cn*NN + row] = f2bf(val);
      } else {
        float val = c[r] + b0[col];
        size_t idx = (size_t)row*Ncols + col;
        if (mode == 2) ((float*)out)[idx] = res[idx] + val;
        else           ((u16*)out)[idx] = f2bf(0.5f*val*(1.f + erff(val*0.70710678f)));
      }
    }
  }
}

// ---------------- barrier-free per-wave fused attention ----------------
// WG = 512 = 8 waves; wave h = head h for 16 q-rows; grid (192 i-tiles, JSPLIT j-chunks).
// Tables are wave-private LDS rows (stride 32 -> bank == index, conflict-free,
// exec-mask-safe; no ds_bpermute anywhere).
__global__ __launch_bounds__(512)
void k_attn(const u16* __restrict__ qb, const u16* __restrict__ kb, const u16* __restrict__ vT,
            const unsigned char* __restrict__ bktP,
            const float* __restrict__ spd_table, const float* __restrict__ slb,
            const u16* __restrict__ meta, const float* __restrict__ ews,
            const float* __restrict__ ett, const int* __restrict__ bptr,
            float* __restrict__ opart, float* __restrict__ mpart, float* __restrict__ lpart){
  __shared__ float s_sc[NH][16][68];
  __shared__ float s_spdw[NH][32];
  __shared__ float s_ettw[NH][32];
  const int tid = threadIdx.x, lane = tid & 63, h = tid >> 6;
  const int it = blockIdx.x, jc = blockIdx.y;
  const int i0 = it * 16;
  // wave-private table init (same-wave ds_write -> ds_read, no barrier needed)
  if (lane < 12) s_spdw[h][lane] = spd_table[lane*8 + h] * 10.f;
  if (lane < 16) s_ettw[h][lane] = ett[lane*8 + h] * 10.f;
  const float slbh = slb[h];
  const int fr = lane & 15, fg = lane >> 4;
  bf16x8 qv = *(const bf16x8*)&qb[(size_t)(i0 + fr)*DM + h*HDIM + fg*8];
  float (*sc)[68] = s_sc[h];
  f32x4 o0 = {0,0,0,0}, o1 = {0,0,0,0};
  float m_run = -3.0e38f, l_run = 0.f;

  for (int jt = jc*(NJT/JSPLIT); jt < (jc+1)*(NJT/JSPLIT); ++jt){
    const int j0 = jt * 64;
    // ---- loads ----
    bf16x8 kf0 = *(const bf16x8*)&kb[(size_t)(j0      + fr)*DM + h*HDIM + fg*8];
    bf16x8 kf1 = *(const bf16x8*)&kb[(size_t)(j0 + 16 + fr)*DM + h*HDIM + fg*8];
    bf16x8 kf2 = *(const bf16x8*)&kb[(size_t)(j0 + 32 + fr)*DM + h*HDIM + fg*8];
    bf16x8 kf3 = *(const bf16x8*)&kb[(size_t)(j0 + 48 + fr)*DM + h*HDIM + fg*8];
    uchar4 bk0 = *(const uchar4*)&bktP[(size_t)(i0 + fg*4 + 0)*NN + j0 + fr*4];
    uchar4 bk1 = *(const uchar4*)&bktP[(size_t)(i0 + fg*4 + 1)*NN + j0 + fr*4];
    uchar4 bk2 = *(const uchar4*)&bktP[(size_t)(i0 + fg*4 + 2)*NN + j0 + fr*4];
    uchar4 bk3 = *(const uchar4*)&bktP[(size_t)(i0 + fg*4 + 3)*NN + j0 + fr*4];
    // ---- QK^T (Q pre-scaled) ----
    f32x4 z = {0,0,0,0};
    f32x4 s0 = MFMA16(qv, kf0, z, 0, 0, 0);
    f32x4 s1 = MFMA16(qv, kf1, z, 0, 0, 0);
    f32x4 s2 = MFMA16(qv, kf2, z, 0, 0, 0);
    f32x4 s3 = MFMA16(qv, kf3, z, 0, 0, 0);
    // ---- scores + spd/diag bias -> wave-private LDS plane ----
    unsigned char bb[4][4] = {{bk0.x,bk0.y,bk0.z,bk0.w},{bk1.x,bk1.y,bk1.z,bk1.w},
                              {bk2.x,bk2.y,bk2.z,bk2.w},{bk3.x,bk3.y,bk3.z,bk3.w}};
    const bool dg_tile = (j0 == (i0 & ~63));
    #pragma unroll
    for (int r = 0; r < 4; r++){
      int row = fg*4 + r;
      #pragma unroll
      for (int c2 = 0; c2 < 4; c2++){
        int col = c2*16 + fr;
        float sv = (c2==0) ? s0[r] : (c2==1) ? s1[r] : (c2==2) ? s2[r] : s3[r];
        float val = sv + s_spdw[h][(int)bb[r][c2]];
        if (dg_tile && (i0 + row == j0 + col)) val += slbh;
        sc[row][col] = val;
      }
    }
    // ---- edge bias: one LDS atomic per edge (plain ds ops, divergence-safe) ----
    {
      int e0 = bptr[it*NJT + jt], e1 = bptr[it*NJT + jt + 1];
      for (int ix = e0 + lane; ix < e1; ix += 64){
        u16 me = meta[ix];
        int il = me & 15, jl = (me >> 4) & 63, tp = me >> 10;
        atomicAdd(&sc[il][jl], s_ettw[h][tp] + 200.f * ews[ix]);
      }
    }
    // ---- read back in A-fragment layout (row fr, cols fg*8.. & 32+fg*8..) ----
    float v[16];
    { f32x4 a = *(const f32x4*)&sc[fr][fg*8];
      v[0]=a[0]; v[1]=a[1]; v[2]=a[2]; v[3]=a[3]; }
    { f32x4 a = *(const f32x4*)&sc[fr][fg*8 + 4];
      v[4]=a[0]; v[5]=a[1]; v[6]=a[2]; v[7]=a[3]; }
    { f32x4 a = *(const f32x4*)&sc[fr][32 + fg*8];
      v[8]=a[0]; v[9]=a[1]; v[10]=a[2]; v[11]=a[3]; }
    { f32x4 a = *(const f32x4*)&sc[fr][32 + fg*8 + 4];
      v[12]=a[0]; v[13]=a[1]; v[14]=a[2]; v[15]=a[3]; }
    // ---- online softmax (row fr; 4 replicas across fg) ----
    float mx = v[0];
    #pragma unroll
    for (int t = 1; t < 16; t++) mx = fmaxf(mx, v[t]);
    mx = fmaxf(mx, __shfl_xor(mx, 16));
    mx = fmaxf(mx, __shfl_xor(mx, 32));
    float mnew = fmaxf(m_run, mx);
    float fac = __expf(m_run - mnew);
    float p[16], ps = 0.f;
    #pragma unroll
    for (int t = 0; t < 16; t++){ p[t] = __expf(v[t] - mnew); ps += p[t]; }
    ps += __shfl_xor(ps, 16);
    ps += __shfl_xor(ps, 32);
    l_run = l_run * fac + ps;
    m_run = mnew;
    // ---- redistribute fac to accumulator rows (fg*4+r), rescale ----
    float f0 = __shfl(fac, fg*4 + 0);
    float f1 = __shfl(fac, fg*4 + 1);
    float f2 = __shfl(fac, fg*4 + 2);
    float f3 = __shfl(fac, fg*4 + 3);
    o0[0]*=f0; o0[1]*=f1; o0[2]*=f2; o0[3]*=f3;
    o1[0]*=f0; o1[1]*=f1; o1[2]*=f2; o1[3]*=f3;
    // ---- P -> bf16 (packed cvt), PV ----
    union { u32 w[4]; bf16x8 v8; } pa0u, pa1u;
    #pragma unroll
    for (int t = 0; t < 4; t++){
      pa0u.w[t] = cvtpk(p[2*t], p[2*t+1]);
      pa1u.w[t] = cvtpk(p[8 + 2*t], p[9 + 2*t]);
    }
    bf16x8 vf00 = *(const bf16x8*)&vT[(size_t)(h*HDIM      + fr)*NN + j0      + fg*8];
    bf16x8 vf01 = *(const bf16x8*)&vT[(size_t)(h*HDIM      + fr)*NN + j0 + 32 + fg*8];
    bf16x8 vf10 = *(const bf16x8*)&vT[(size_t)(h*HDIM + 16 + fr)*NN + j0      + fg*8];
    bf16x8 vf11 = *(const bf16x8*)&vT[(size_t)(h*HDIM + 16 + fr)*NN + j0 + 32 + fg*8];
    o0 = MFMA16(pa0u.v8, vf00, o0, 0, 0, 0);
    o0 = MFMA16(pa1u.v8, vf01, o0, 0, 0, 0);
    o1 = MFMA16(pa0u.v8, vf10, o1, 0, 0, 0);
    o1 = MFMA16(pa1u.v8, vf11, o1, 0, 0, 0);
  }

  // ---- write unnormalized partials ----
  float* ob = opart + (size_t)jc*NN*DM;
  #pragma unroll
  for (int r = 0; r < 4; r++){
    size_t row = i0 + fg*4 + r;
    ob[row*DM + h*HDIM + fr]      = o0[r];
    ob[row*DM + h*HDIM + 16 + fr] = o1[r];
  }
  if (fg == 0){
    mpart[jc*NN*NH + (i0 + fr)*NH + h] = m_run;
    lpart[jc*NN*NH + (i0 + fr)*NH + h] = l_run;
  }
}

// ---------------- combine J-split partials ----------------
__global__ __launch_bounds__(256)
void k_reduce(const float* __restrict__ opart, const float* __restrict__ mpart,
              const float* __restrict__ lpart, u16* __restrict__ aob){
  int row = blockIdx.x, col = threadIdx.x, h = col >> 5;
  float m[JSPLIT], l[JSPLIT];
  float M = -3.0e38f;
  #pragma unroll
  for (int jc = 0; jc < JSPLIT; jc++){
    m[jc] = mpart[jc*NN*NH + row*NH + h];
    l[jc] = lpart[jc*NN*NH + row*NH + h];
    M = fmaxf(M, m[jc]);
  }
  float L = 0.f, acc = 0.f;
  #pragma unroll
  for (int jc = 0; jc < JSPLIT; jc++){
    float w = __expf(m[jc] - M);
    L += l[jc] * w;
    acc += opart[(size_t)jc*NN*DM + (size_t)row*DM + col] * w;
  }
  aob[(size_t)row*DM + col] = f2bf(acc / L);
}

// ---------------- launcher ----------------
extern "C" void kernel_launch(void* const* d_in, const int* in_sizes, int n_in,
                              void* d_out, int out_size, void* d_ws, size_t ws_size,
                              hipStream_t stream){
  const float* x     = (const float*)d_in[0];
  const int*   ei    = (const int*)d_in[1];
  const int*   etyp  = (const int*)d_in[2];
  const float* pos   = (const float*)d_in[3];
  const float* ewin  = (const float*)d_in[4];
  const float* Wq    = (const float*)d_in[5];
  const float* bq    = (const float*)d_in[6];
  const float* Wk    = (const float*)d_in[7];
  const float* bk    = (const float*)d_in[8];
  const float* Wv    = (const float*)d_in[9];
  const float* bv    = (const float*)d_in[10];
  const float* Wo    = (const float*)d_in[11];
  const float* bo    = (const float*)d_in[12];
  const float* spd   = (const float*)d_in[13];
  const float* ett   = (const float*)d_in[14];
  const float* slb   = (const float*)d_in[15];
  const float* inde  = (const float*)d_in[16];
  const float* outde = (const float*)d_in[17];
  const float* dsc   = (const float*)d_in[18];
  const float* ln1g  = (const float*)d_in[19];
  const float* ln1b  = (const float*)d_in[20];
  const float* ln2g  = (const float*)d_in[21];
  const float* ln2b  = (const float*)d_in[22];
  const float* W1    = (const float*)d_in[23];
  const float* b1    = (const float*)d_in[24];
  const float* W2    = (const float*)d_in[25];
  const float* b2    = (const float*)d_in[26];
  const int* src = ei;
  const int* dst = ei + NE;

  char* p = (char*)d_ws;
  auto alloc = [&](size_t bytes) -> void* {
    void* r = (void*)p;
    p += (bytes + 255) & ~(size_t)255;
    return r;
  };
  // zeroed region (contiguous): deg_in, deg_out, bcnt, bfill
  int*  deg_in  = (int*)alloc(NN*4);
  int*  deg_out = (int*)alloc(NN*4);
  int*  bcnt    = (int*)alloc(9216*4);
  int*  bfill   = (int*)alloc(9216*4);
  int*  bptr    = (int*)alloc(9217*4);
  u16*  meta    = (u16*)alloc(NE*2);
  float* ews    = (float*)alloc(NE*4);
  unsigned char* bktP = (unsigned char*)alloc((size_t)NN*NN);
  float* xb     = (float*)alloc((size_t)NN*DM*4);
  float* x2     = (float*)alloc((size_t)NN*DM*4);
  u16*  xnb     = (u16*)alloc((size_t)NN*DM*2);
  u16*  x2nb    = (u16*)alloc((size_t)NN*DM*2);
  u16*  qb      = (u16*)alloc((size_t)NN*DM*2);   // qb, kb contiguous
  u16*  kb      = (u16*)alloc((size_t)NN*DM*2);
  u16*  vT      = (u16*)alloc((size_t)NN*DM*2);
  u16*  aob     = (u16*)alloc((size_t)NN*DM*2);
  u16*  h1b     = (u16*)alloc((size_t)NN*DFF*2);
  float* opart  = (float*)alloc((size_t)JSPLIT*NN*DM*4);
  float* mpart  = (float*)alloc((size_t)JSPLIT*NN*NH*4);
  float* lpart  = (float*)alloc((size_t)JSPLIT*NN*NH*4);
  u16*  Wqkvot  = (u16*)alloc(4*65536*2);          // Wq^T,Wk^T,Wv^T,Wo^T contiguous
  u16*  W1t     = (u16*)alloc(262144*2);
  u16*  W2t     = (u16*)alloc(262144*2);

  hipMemsetAsync(deg_in, 0, (2*NN + 2*9216)*4, stream);

  k_deg<<<NE/256, 256, 0, stream>>>(src, dst, deg_out, deg_in, bcnt);
  k_scan<<<1, 1024, 0, stream>>>(bcnt, bptr);
  k_scatter<<<NE/256, 256, 0, stream>>>(src, dst, etyp, ewin, bptr, bfill, meta, ews);
  k_bucket<<<dim3(3, NN), 1024, 0, stream>>>(pos, bktP);
  k_trans<<<768, 256, 0, stream>>>(Wq, Wk, Wv, Wo, W1, W2, Wqkvot, W1t, W2t);
  k_ln<<<NN, 256, 0, stream>>>(x, deg_in, deg_out, inde, outde, dsc, ln1g, ln1b, xb, xnb);

  // fused QKV: Bt = [Wq^T; Wk^T; Wv^T] (768 x 256)
  k_gemm<<<dim3(12, 48), 256, 0, stream>>>(xnb, Wqkvot, bq, bk, bv, nullptr,
                                           qb, vT, DM, 768, 5);

  k_attn<<<dim3(NIT, JSPLIT), 512, 0, stream>>>(qb, kb, vT, bktP, spd, slb, meta, ews,
                                                ett, bptr, opart, mpart, lpart);
  k_reduce<<<NN, 256, 0, stream>>>(opart, mpart, lpart, aob);

  u16* Wot = Wqkvot + 3*65536;
  k_gemm<<<dim3(4, 48), 256, 0, stream>>>(aob, Wot, bo, nullptr, nullptr, xb,
                                          x2, nullptr, DM, DM, 2);
  k_ln<<<NN, 256, 0, stream>>>(x2, nullptr, nullptr, nullptr, nullptr, nullptr,
                               ln2g, ln2b, nullptr, x2nb);
  k_gemm<<<dim3(16, 48), 256, 0, stream>>>(x2nb, W1t, b1, nullptr, nullptr, nullptr,
                                           h1b, nullptr, DM, DFF, 3);
  k_gemm<<<dim3(4, 48), 256, 0, stream>>>(h1b, W2t, b2, nullptr, nullptr, x2,
                                          d_out, nullptr, DFF, DM, 2);
}